// Round 2
// baseline (3891.859 us; speedup 1.0000x reference)
//
#include <hip/hip_runtime.h>

#define Bn 256
#define Tn 2048
#define Dn 40
#define Hn 128
#define Cn 35

typedef _Float16 h2 __attribute__((ext_vector_type(2)));
typedef int int4v __attribute__((ext_vector_type(4)));

__device__ __forceinline__ int imin(int a, int b) { return a < b ? a : b; }

__device__ __forceinline__ int sdot4(int a, int b, int c) {
#if __has_builtin(__builtin_amdgcn_sdot4)
  return __builtin_amdgcn_sdot4(a, b, c, false);
#else
  int r = c;
#pragma unroll
  for (int i = 0; i < 4; ++i)
    r += ((int)(a << (24 - 8 * i)) >> 24) * ((int)(b << (24 - 8 * i)) >> 24);
  return r;
#endif
}

__device__ __forceinline__ float fdot2f(h2 a, h2 b, float c) {
#if __has_builtin(__builtin_amdgcn_fdot2)
  return __builtin_amdgcn_fdot2(a, b, c, false);
#else
  return c + (float)(a[0]) * (float)(b[0]) + (float)(a[1]) * (float)(b[1]);
#endif
}

__device__ __forceinline__ h2 bch(int u) { return __builtin_bit_cast(h2, u); }

__device__ __forceinline__ int pk2i(float a, float b) {  // two f16 in one word
  h2 r; r[0] = (_Float16)a; r[1] = (_Float16)b;
  return __builtin_bit_cast(int, r);
}

__device__ __forceinline__ float rcpf_(float x) {
#if __has_builtin(__builtin_amdgcn_rcpf)
  return __builtin_amdgcn_rcpf(x);
#else
  return 1.f / x;
#endif
}

__device__ __forceinline__ float sigm(float v) {
  v = fmaxf(fminf(v, 60.f), -60.f);
  return rcpf_(1.f + __expf(-v));
}

__device__ __forceinline__ float tanha(float v) {
  v = fmaxf(fminf(v, 15.f), -15.f);
  const float e = __expf(2.f * v);
  return (e - 1.f) * rcpf_(e + 1.f);
}

__device__ __forceinline__ int q8c(float v) {  // round+clamp to [-127,127]
  v = fminf(fmaxf(v, -127.f), 127.f);
  return (int)__builtin_rintf(v);
}

__device__ __forceinline__ int pk4(int a, int b, int c, int d) {
  return (a & 255) | ((b & 255) << 8) | ((c & 255) << 16) | (d << 24);
}

#if __has_builtin(__builtin_amdgcn_global_load_lds)
#define HAVE_GLDS 1
__device__ __forceinline__ void gl_lds16(const float* g, float* l) {
  __builtin_amdgcn_global_load_lds(
      (const __attribute__((address_space(1))) unsigned int*)(const void*)g,
      (__attribute__((address_space(3))) unsigned int*)(void*)l, 16, 0, 0);
}
#endif

// quantize 128 f32 weights -> 32 packed-i8 words + scale (rowmax/127)
__device__ __forceinline__ void quantW128(const float* __restrict__ p,
                                          int* __restrict__ q, float& sc) {
  float m = 1e-30f;
#pragma unroll
  for (int i = 0; i < 32; ++i) {
    const float4 v = reinterpret_cast<const float4*>(p)[i];
    m = fmaxf(m, fmaxf(fmaxf(fabsf(v.x), fabsf(v.y)),
                       fmaxf(fabsf(v.z), fabsf(v.w))));
  }
  const float inv = 127.f / m;
  sc = m * (1.f / 127.f);
#pragma unroll
  for (int i = 0; i < 32; ++i) {
    const float4 v = reinterpret_cast<const float4*>(p)[i];
    q[i] = pk4(q8c(v.x * inv), q8c(v.y * inv), q8c(v.z * inv), q8c(v.w * inv));
  }
}

// readlane word w (0..319) from 5-reg stash (lane L holds flat[L+64k])
#define RLST(w) __builtin_amdgcn_readlane(                                  \
    ((w) < 64 ? st0 : (w) < 128 ? st1 : (w) < 192 ? st2 : (w) < 256 ? st3  \
                                                        : st4), (w) & 63)

// r8: barrier-free dataflow. r6/r7 post-mortem: wall ~3000cy/step with only
// ~1100cy VALU issue -- the workgroup-wide s_barrier correlates all waves'
// stall windows (slowest wave paces everyone, latency never overlaps).
// Restructure into decoupled chains synced by per-wave LDS progress flags:
//   waves 0-1: L0 recurrence (lane = unit, all 4 Whh0 rows in 128 VGPRs,
//              gates+activation fully in-lane, no exchange)
//   waves 2-3: L1 recurrence (Whh1 rows in regs; fp32 ih-term from ring)
//   waves 4-7: helpers -- Wih1.h0 terms (2 rows/lane -> 4-deep term ring)
//              + whole x pipeline (glds tl==2, vmcnt+f16 convert tl==5,
//              2-row xproj burst slices tl==8..15; Wih0 cols in 40 regs,
//              s_w0x LDS deleted)
// Sync protocol: h stashes double-buffered, term ring 4-deep; flag[wv]=t+1
// published after lgkmcnt(0) (all step-t LDS reads AND writes done); pollers
// read all 8 flags in one 2x ds_read_b128 asm (in-order DS pipe => observing
// flag>=t proves partner's data writes landed before our subsequent reads).
// Cached flags skip the poll when a previous observation already suffices
// (monotone flags => always safe). Each SIMD = 1 chain wave + 1 helper wave,
// mutually decoupled -> stalls overlap instead of adding.
__global__ __launch_bounds__(512) void lstm2_fused(
    const float* __restrict__ x,
    const int*   __restrict__ length,
    const float* __restrict__ Wih0, const float* __restrict__ Whh0,
    const float* __restrict__ bih0, const float* __restrict__ bhh0,
    const float* __restrict__ Wih1, const float* __restrict__ Whh1,
    const float* __restrict__ bih1, const float* __restrict__ bhh1,
    const float* __restrict__ gam,  const float* __restrict__ bet,
    const float* __restrict__ fcw,  const float* __restrict__ fcb,
    float* __restrict__ out)
{
  __shared__ __align__(16) float s_xraw[192 * 4];  // 3 KiB raw x chunk (glds dest)
  __shared__ int   s_xh2[2][320];                  // 2.5 KiB f16 x chunks
  __shared__ float s_xp[2][16][512];               // 64 KiB x-projection
  __shared__ float s_term[4][128][4];              // 8 KiB ih-term ring (i,f,g,o)
  __shared__ int   s_h0q[2][32];                   // dbuf packed i8 h0
  __shared__ int   s_h1q[2][32];                   // dbuf packed i8 h1
  __shared__ __align__(32) int s_flag[8];          // per-wave progress
  __shared__ float s_h1f[128];
  __shared__ float s_hn[128];

  const int tid  = threadIdx.x;
  const int lane = tid & 63;
  const int wv   = tid >> 6;          // wave 0..7
  const int b    = blockIdx.x;
  const int len  = length[b];         // 1..2048

  // ---- prologue: chunk-0 raw x prefetch (waves 4-6), zero state ----
  if (wv >= 4 && wv <= 6) {
    const int seg0 = wv - 4;
    int seg = seg0 * 64 + lane;
    if (seg >= 160) seg = 0;  // clamp (lands in unused s_xraw tail)
#if HAVE_GLDS
    gl_lds16(x + (size_t)b * Tn * Dn + seg * 4, &s_xraw[seg0 * 256]);
#else
    *(float4*)&s_xraw[seg * 4] =
        *(const float4*)(x + (size_t)b * Tn * Dn + seg * 4);
#endif
  }
  if (tid < 32) {
    s_h0q[0][tid] = 0; s_h0q[1][tid] = 0;
    s_h1q[0][tid] = 0; s_h1q[1][tid] = 0;
  }
  if (tid < 8) s_flag[tid] = 0;

  // ---- role-specific weight setup (overlaps glds) ----
  int qq0[32], qq1[32], qq2[32], qq3[32];
  int wpa[20], wpb[20];
  float sc0 = 0.f, sc1 = 0.f, sc2 = 0.f, sc3 = 0.f;
  float bs0 = 0.f, bs1 = 0.f, bs2 = 0.f, bs3 = 0.f;

  if (wv < 2) {             // L0 chain: unit u -> Whh0 rows u,u+128,u+256,u+384
    const int u = (wv << 6) | lane;
    quantW128(Whh0 + (size_t)(u)       * Hn, qq0, sc0);
    quantW128(Whh0 + (size_t)(u + 128) * Hn, qq1, sc1);
    quantW128(Whh0 + (size_t)(u + 256) * Hn, qq2, sc2);
    quantW128(Whh0 + (size_t)(u + 384) * Hn, qq3, sc3);
    bs0 = bih0[u]       + bhh0[u];
    bs1 = bih0[u + 128] + bhh0[u + 128];
    bs2 = bih0[u + 256] + bhh0[u + 256];
    bs3 = bih0[u + 384] + bhh0[u + 384];
  } else if (wv < 4) {      // L1 chain: Whh1 rows (biases folded into term)
    const int u = ((wv - 2) << 6) | lane;
    quantW128(Whh1 + (size_t)(u)       * Hn, qq0, sc0);
    quantW128(Whh1 + (size_t)(u + 128) * Hn, qq1, sc1);
    quantW128(Whh1 + (size_t)(u + 256) * Hn, qq2, sc2);
    quantW128(Whh1 + (size_t)(u + 384) * Hn, qq3, sc3);
  } else {                  // helpers: Wih1 rows hl,hl+256 + Wih0 cols hl,hl+256
    const int hl = ((wv - 4) << 6) | lane;  // 0..255
    quantW128(Wih1 + (size_t)hl * Hn, qq0, sc0);
    quantW128(Wih1 + (size_t)(hl + 256) * Hn, qq1, sc1);
    bs0 = bih1[hl]       + bhh1[hl];
    bs1 = bih1[hl + 256] + bhh1[hl + 256];
    const float* p0 = Wih0 + (size_t)hl * Dn;
    const float* p1 = Wih0 + (size_t)(hl + 256) * Dn;
#pragma unroll
    for (int k = 0; k < 20; ++k) {
      wpa[k] = pk2i(p0[2 * k], p0[2 * k + 1]);
      wpb[k] = pk2i(p1[2 * k], p1[2 * k + 1]);
    }
  }
  sc0 *= (1.f / 127.f);  // fold fixed h-scale (h quantized at 127)
  sc1 *= (1.f / 127.f);
  sc2 *= (1.f / 127.f);
  sc3 *= (1.f / 127.f);

  __syncthreads();  // glds drained; zeros visible

  // ---- chunk 0: convert to f16 ----
  if (wv >= 4) {
    const int hl = ((wv - 4) << 6) | lane;
    if (hl < 160) {
      const float4 v = *(const float4*)&s_xraw[4 * hl];
      s_xh2[0][2 * hl]     = pk2i(v.x, v.y);
      s_xh2[0][2 * hl + 1] = pk2i(v.z, v.w);
    }
  }
  __syncthreads();

  // ---- chunk 0: project all 16 rows ----
  if (wv >= 4) {
    const int hl = ((wv - 4) << 6) | lane;
    const int* flat = &s_xh2[0][0];
    const int st0 = flat[lane], st1 = flat[lane + 64], st2 = flat[lane + 128],
              st3 = flat[lane + 192], st4 = flat[lane + 256];
#pragma unroll 1
    for (int r = 0; r < 16; ++r) {
      float a0 = 0.f, a1 = 0.f;
#pragma unroll
      for (int w = 0; w < 20; ++w) {
        const h2 s = bch(RLST(20 * r + w));
        a0 = fdot2f(s, bch(wpa[w]), a0);
        a1 = fdot2f(s, bch(wpb[w]), a1);
      }
      s_xp[0][r][hl]       = a0;
      s_xp[0][r][hl + 256] = a1;
    }
  }
  __syncthreads();

  const __attribute__((address_space(3))) int* flagp3 =
      (const __attribute__((address_space(3))) int*)(const void*)s_flag;
  int4v f03 = {0, 0, 0, 0}, f47 = {0, 0, 0, 0};

#define READFLAGS()                                                          \
  asm volatile("ds_read_b128 %0, %2\n\tds_read_b128 %1, %2 offset:16\n\t"    \
               "s_waitcnt lgkmcnt(0)"                                        \
               : "=v"(f03), "=v"(f47) : "v"(flagp3) : "memory")
#define HMIN4 imin(imin(f47[0], f47[1]), imin(f47[2], f47[3]))
#define PUBLISH(val)                                                         \
  do {                                                                       \
    asm volatile("s_waitcnt lgkmcnt(0)" ::: "memory");                       \
    ((volatile int*)s_flag)[wv] = (val);                                     \
  } while (0)

  if (wv < 2) {
    // ================= L0 chain =================
    const int u = (wv << 6) | lane;
    float c0 = 0.f;
#pragma unroll 1
    for (int t = 0; t < len; ++t) {
      const int tl = t & 15;
      // partner wrote h0(t-1) & read h0(t-2); helpers read h0(t-2) / chunk ready
      const int needH = t - (tl == 0 ? 0 : 1);
      {
        int pf = (wv == 0) ? f03[1] : f03[0];
        if (!(pf >= t && HMIN4 >= needH)) {
          for (;;) {
            READFLAGS();
            pf = (wv == 0) ? f03[1] : f03[0];
            if (pf >= t && HMIN4 >= needH) break;
            __builtin_amdgcn_s_sleep(1);
          }
        }
      }
      const int vq = s_h0q[(t + 1) & 1][lane & 31];  // h0(t-1)
      const int cs = (t >> 4) & 1;
      const float xI = s_xp[cs][tl][u];
      const float xF = s_xp[cs][tl][u + 128];
      const float xG = s_xp[cs][tl][u + 256];
      const float xO = s_xp[cs][tl][u + 384];
      int aI = 0, aF = 0, aG = 0, aO = 0;
#pragma unroll
      for (int j = 0; j < 32; ++j) {
        const int s = __builtin_amdgcn_readlane(vq, j);
        aI = sdot4(s, qq0[j], aI);
        aF = sdot4(s, qq1[j], aF);
        aG = sdot4(s, qq2[j], aG);
        aO = sdot4(s, qq3[j], aO);
      }
      const float gi = bs0 + xI + (float)aI * sc0;
      const float gf = bs1 + xF + (float)aF * sc1;
      const float gg = bs2 + xG + (float)aG * sc2;
      const float go = bs3 + xO + (float)aO * sc3;
      c0 = sigm(gf) * c0 + sigm(gi) * tanha(gg);
      const float h = sigm(go) * tanha(c0);
      ((signed char*)s_h0q)[((t & 1) << 7) + u] =
          (signed char)(int)__builtin_rintf(h * 127.f);
      PUBLISH(t + 1);
      READFLAGS();  // refresh cache; often skips next step's poll
    }
  } else if (wv < 4) {
    // ================= L1 chain =================
    const int u = ((wv - 2) << 6) | lane;
    float c1 = 0.f;
#pragma unroll 1
    for (int t = 0; t < len; ++t) {
      {
        int pf = (wv == 2) ? f03[3] : f03[2];
        if (!(pf >= t && HMIN4 >= t + 1)) {  // term(t) ready; partner ok
          for (;;) {
            READFLAGS();
            pf = (wv == 2) ? f03[3] : f03[2];
            if (pf >= t && HMIN4 >= t + 1) break;
            __builtin_amdgcn_s_sleep(1);
          }
        }
      }
      const int vq = s_h1q[(t + 1) & 1][lane & 31];  // h1(t-1)
      const float4 tv = *(const float4*)&s_term[t & 3][u][0];
      int aI = 0, aF = 0, aG = 0, aO = 0;
#pragma unroll
      for (int j = 0; j < 32; ++j) {
        const int s = __builtin_amdgcn_readlane(vq, j);
        aI = sdot4(s, qq0[j], aI);
        aF = sdot4(s, qq1[j], aF);
        aG = sdot4(s, qq2[j], aG);
        aO = sdot4(s, qq3[j], aO);
      }
      const float gi = tv.x + (float)aI * sc0;
      const float gf = tv.y + (float)aF * sc1;
      const float gg = tv.z + (float)aG * sc2;
      const float go = tv.w + (float)aO * sc3;
      c1 = sigm(gf) * c1 + sigm(gi) * tanha(gg);
      const float h = sigm(go) * tanha(c1);
      if (t == len - 1) s_h1f[u] = h;
      ((signed char*)s_h1q)[((t & 1) << 7) + u] =
          (signed char)(int)__builtin_rintf(h * 127.f);
      PUBLISH(t + 1);
      READFLAGS();
    }
  } else {
    // ================= helpers =================
    const int hl   = ((wv - 4) << 6) | lane;  // 0..255
    const int u    = hl & 127;
    const int gsel = hl >> 7;  // 0 -> gates {i,g}; 1 -> gates {f,o}
#pragma unroll 1
    for (int t = 0; t < len; ++t) {
      const int tl = t & 15;
      // L0 wrote h0(t); L1 freed ring slot; tl5/tl8 gates for x pipeline
      const int needX = (tl == 5) ? (t - 5) : (tl == 8) ? t : -1000000000;
      if (!(f03[0] >= t + 1 && f03[1] >= t + 1 &&
            f03[2] >= t - 3 && f03[3] >= t - 3 && HMIN4 >= needX)) {
        for (;;) {
          READFLAGS();
          if (f03[0] >= t + 1 && f03[1] >= t + 1 &&
              f03[2] >= t - 3 && f03[3] >= t - 3 && HMIN4 >= needX) break;
          __builtin_amdgcn_s_sleep(1);
        }
      }
      if (tl == 2 && wv <= 6) {  // async prefetch next raw x chunk
        const int t0 = (t & ~15) + 16;
        if (t0 <= Tn - 16) {
          const int seg0 = wv - 4;
          int seg = seg0 * 64 + lane;
          if (seg >= 160) seg = 0;
#if HAVE_GLDS
          gl_lds16(x + ((size_t)b * Tn + t0) * Dn + seg * 4,
                   &s_xraw[seg0 * 256]);
#else
          *(float4*)&s_xraw[seg * 4] =
              *(const float4*)(x + ((size_t)b * Tn + t0) * Dn + seg * 4);
#endif
        }
      }
      // ---- ih-term dot over h0(t) ----
      const int vq = s_h0q[t & 1][lane & 31];
      int aA = 0, aB = 0;
#pragma unroll
      for (int j = 0; j < 32; ++j) {
        const int s = __builtin_amdgcn_readlane(vq, j);
        aA = sdot4(s, qq0[j], aA);
        aB = sdot4(s, qq1[j], aB);
      }
      s_term[t & 3][u][gsel]     = bs0 + (float)aA * sc0;
      s_term[t & 3][u][gsel + 2] = bs1 + (float)aB * sc1;
      // ---- x pipeline ----
      if (tl == 5 && wv <= 6) {  // raw -> f16 (own wave's glds region)
#if HAVE_GLDS
        asm volatile("s_waitcnt vmcnt(0)" ::: "memory");
#endif
        if (hl < 160) {
          const float4 v = *(const float4*)&s_xraw[4 * hl];
          const int nb = ((t >> 4) & 1) ^ 1;
          s_xh2[nb][2 * hl]     = pk2i(v.x, v.y);
          s_xh2[nb][2 * hl + 1] = pk2i(v.z, v.w);
        }
      }
      if (tl >= 8) {  // project 2 rows of next chunk
        const int nb = ((t >> 4) & 1) ^ 1;
        const int r0 = (tl - 8) * 2;
        const int* flat = &s_xh2[nb][0];
        const int st0 = flat[lane], st1 = flat[lane + 64],
                  st2 = flat[lane + 128], st3 = flat[lane + 192],
                  st4 = flat[lane + 256];
#pragma unroll
        for (int r = r0; r < r0 + 2; ++r) {
          float a0 = 0.f, a1 = 0.f;
#pragma unroll
          for (int w = 0; w < 20; ++w) {
            const h2 s = bch(RLST(20 * r + w));
            a0 = fdot2f(s, bch(wpa[w]), a0);
            a1 = fdot2f(s, bch(wpb[w]), a1);
          }
          s_xp[nb][r][hl]       = a0;
          s_xp[nb][r][hl + 256] = a1;
        }
      }
      PUBLISH(t + 1);
      READFLAGS();
    }
  }

  __syncthreads();  // all chains done; s_h1f complete

  // ---- LayerNorm over H on wave 0 ----
  if (tid < 64) {
    const float a = s_h1f[tid], d = s_h1f[64 + tid];
    float s = a + d, q = a * a + d * d;
#pragma unroll
    for (int m = 32; m >= 1; m >>= 1) {
      s += __shfl_xor(s, m, 64);
      q += __shfl_xor(q, m, 64);
    }
    const float mu = s * (1.f / 128.f);
    float var = q * (1.f / 128.f) - mu * mu;
    var = fmaxf(var, 0.f);
    const float rstd = rsqrtf(var + 1e-5f);
    s_hn[tid]      = (a - mu) * rstd * gam[tid]      + bet[tid];
    s_hn[64 + tid] = (d - mu) * rstd * gam[64 + tid] + bet[64 + tid];
  }
  __syncthreads();

  // ---- FC head ----
  if (tid < Cn) {
    float acc = fcb[tid];
    const float* wp = fcw + tid * Hn;
#pragma unroll 4
    for (int k = 0; k < Hn; ++k) acc += s_hn[k] * wp[k];
    out[(size_t)b * Cn + tid] = acc;
  }
}

extern "C" void kernel_launch(void* const* d_in, const int* in_sizes, int n_in,
                              void* d_out, int out_size, void* d_ws, size_t ws_size,
                              hipStream_t stream) {
  (void)in_sizes; (void)n_in; (void)d_ws; (void)ws_size; (void)out_size;
  lstm2_fused<<<dim3(Bn), dim3(512), 0, stream>>>(
      (const float*)d_in[0],  (const int*)d_in[1],
      (const float*)d_in[2],  (const float*)d_in[3],
      (const float*)d_in[4],  (const float*)d_in[5],
      (const float*)d_in[6],  (const float*)d_in[7],
      (const float*)d_in[8],  (const float*)d_in[9],
      (const float*)d_in[10], (const float*)d_in[11],
      (const float*)d_in[12], (const float*)d_in[13],
      (float*)d_out);
}

// Round 3
// 2494.076 us; speedup vs baseline: 1.5604x; 1.5604x over previous
//
#include <hip/hip_runtime.h>

#define Bn 256
#define Tn 2048
#define Dn 40
#define Hn 128
#define Cn 35

typedef _Float16 h2 __attribute__((ext_vector_type(2)));

__device__ __forceinline__ int sdot4(int a, int b, int c) {
#if __has_builtin(__builtin_amdgcn_sdot4)
  return __builtin_amdgcn_sdot4(a, b, c, false);
#else
  int r = c;
#pragma unroll
  for (int i = 0; i < 4; ++i)
    r += ((int)(a << (24 - 8 * i)) >> 24) * ((int)(b << (24 - 8 * i)) >> 24);
  return r;
#endif
}

__device__ __forceinline__ float fdot2f(h2 a, h2 b, float c) {
#if __has_builtin(__builtin_amdgcn_fdot2)
  return __builtin_amdgcn_fdot2(a, b, c, false);
#else
  return c + (float)(a[0]) * (float)(b[0]) + (float)(a[1]) * (float)(b[1]);
#endif
}

__device__ __forceinline__ h2 bch(int u) { return __builtin_bit_cast(h2, u); }

__device__ __forceinline__ int pk2i(float a, float b) {  // two f16 in one word
  h2 r; r[0] = (_Float16)a; r[1] = (_Float16)b;
  return __builtin_bit_cast(int, r);
}

__device__ __forceinline__ float rcpf_(float x) {
#if __has_builtin(__builtin_amdgcn_rcpf)
  return __builtin_amdgcn_rcpf(x);
#else
  return 1.f / x;
#endif
}

__device__ __forceinline__ float sigm(float v) {
  v = fmaxf(fminf(v, 60.f), -60.f);
  return rcpf_(1.f + __expf(-v));
}

__device__ __forceinline__ float tanha(float v) {
  v = fmaxf(fminf(v, 15.f), -15.f);
  const float e = __expf(2.f * v);
  return (e - 1.f) * rcpf_(e + 1.f);
}

__device__ __forceinline__ int q8c(float v) {  // round+clamp to [-127,127]
  v = fminf(fmaxf(v, -127.f), 127.f);
  return (int)__builtin_rintf(v);
}

__device__ __forceinline__ int pk4(int a, int b, int c, int d) {
  return (a & 255) | ((b & 255) << 8) | ((c & 255) << 16) | (d << 24);
}

// DPP quad-perm xor-1 / xor-2 (full-rate VALU cross-lane within quads)
__device__ __forceinline__ int dpp_x1(int v) {
  return __builtin_amdgcn_update_dpp(0, v, 0xB1, 0xF, 0xF, true);
}
__device__ __forceinline__ int dpp_x2(int v) {
  return __builtin_amdgcn_update_dpp(0, v, 0x4E, 0xF, 0xF, true);
}

#if __has_builtin(__builtin_amdgcn_global_load_lds)
#define HAVE_GLDS 1
__device__ __forceinline__ void gl_lds16(const float* g, float* l) {
  __builtin_amdgcn_global_load_lds(
      (const __attribute__((address_space(1))) unsigned int*)(const void*)g,
      (__attribute__((address_space(3))) unsigned int*)(void*)l, 16, 0, 0);
}
#endif

// quantize 128 f32 weights -> 32 packed-i8 words + scale (rowmax/127)
__device__ __forceinline__ void quantW128(const float* __restrict__ p,
                                          int* __restrict__ q, float& sc) {
  float m = 1e-30f;
#pragma unroll
  for (int i = 0; i < 32; ++i) {
    const float4 v = reinterpret_cast<const float4*>(p)[i];
    m = fmaxf(m, fmaxf(fmaxf(fabsf(v.x), fabsf(v.y)),
                       fmaxf(fabsf(v.z), fabsf(v.w))));
  }
  const float inv = 127.f / m;
  sc = m * (1.f / 127.f);
#pragma unroll
  for (int i = 0; i < 32; ++i) {
    const float4 v = reinterpret_cast<const float4*>(p)[i];
    q[i] = pk4(q8c(v.x * inv), q8c(v.y * inv), q8c(v.z * inv), q8c(v.w * inv));
  }
}

// readlane word w (0..319) from 5-reg stash (lane L holds flat[L+64k])
#define RLST(w) __builtin_amdgcn_readlane(                                  \
    ((w) < 64 ? st0 : (w) < 128 ? st1 : (w) < 192 ? st2 : (w) < 256 ? st3  \
                                                        : st4), (w) & 63)

#define MEMBAR() asm volatile("" ::: "memory")
#define POLL_GE(idx, val, cache)                                             \
  do {                                                                       \
    if ((cache) < (val)) {                                                   \
      do { (cache) = *(volatile int*)&s_flag[idx]; } while ((cache) < (val));\
    }                                                                        \
    MEMBAR();                                                                \
  } while (0)
#define PUBLISH(idx, val)                                                    \
  do {                                                                       \
    MEMBAR();                                                                \
    asm volatile("s_waitcnt lgkmcnt(0)" ::: "memory");                       \
    *(volatile int*)&s_flag[idx] = (val);                                    \
  } while (0)

// r9: zero-hop recurrences. r8 post-mortem calibrated a cross-wave LDS hop
// (write -> visibility -> read, barrier or flag) at ~400-600cy; r6 had 2
// hops/step (2870cy), r8 accidentally serialized 2 hops INTO the loop
// (4450cy). Fix: each recurrence lives in ONE wave with ALL its weights in
// registers (8 rows/lane = 256 VGPR; __launch_bounds__(256,1) -> 1 wave/SIMD)
// and h repacked to dot-ready i8 words IN-REGISTER via DPP quad-perm
// or-reduce (no LDS on the h0->h0 / h1->h1 paths at all):
//   wave0 L0:  h0 dot = 32 readlane(own regs) + 256 sdot4; act in-lane
//   wave1 L1:  h1 dot likewise; consumes term(t) from ring (exact, no lag)
//   wave2 TERM: Wih1 . h0(t) from L0's 4-deep export ring -> term ring
//   wave3 XP:  glds x -> f16 -> Wih0 projection, 16-step chunks, 2 buffers
// Cross-wave edges (L0->TERM->L1, XP->L0, L0-slot-reuse) are feed-forward
// with ring slack >= 3 steps: hop latency pipelines OFF the critical path.
// Flags: monotone per-wave counters; publish = lgkmcnt(0) + ds_write (DS
// in-order per wave => flag implies data visible); polls use cached values
// refreshed opportunistically under the publish wait; compiler memory
// barriers stop LDS-load speculation across polls.
__global__ __launch_bounds__(256, 1) void lstm2_fused(
    const float* __restrict__ x,
    const int*   __restrict__ length,
    const float* __restrict__ Wih0, const float* __restrict__ Whh0,
    const float* __restrict__ bih0, const float* __restrict__ bhh0,
    const float* __restrict__ Wih1, const float* __restrict__ Whh1,
    const float* __restrict__ bih1, const float* __restrict__ bhh1,
    const float* __restrict__ gam,  const float* __restrict__ bet,
    const float* __restrict__ fcw,  const float* __restrict__ fcb,
    float* __restrict__ out)
{
  __shared__ __align__(16) float s_xraw[160 * 4];  // 2.5 KiB raw x chunk
  __shared__ int   s_xh2[320];                     // 1.25 KiB f16 x chunk
  __shared__ float s_xp[2][16][8][64];             // 64 KiB x-projection
  __shared__ float s_term[4][8][64];               // 8 KiB ih-term ring
  __shared__ int   s_h0q[4][32];                   // 4-deep packed i8 h0 ring
  __shared__ int   s_flag[4];                      // fL0,fT,fL1,fX
  __shared__ float s_h1f[128];
  __shared__ float s_hn[128];

  const int tid  = threadIdx.x;
  const int lane = tid & 63;
  const int wv   = tid >> 6;          // wave 0..3 (one per SIMD)
  const int b    = blockIdx.x;
  const int len  = length[b];         // 1..2048

  if (tid < 4) s_flag[tid] = 0;
  __syncthreads();

  // Lane L of a recurrence/term wave owns gate-rows r_k = L + 64k, k=0..7:
  //   unitA=L:    k=0(i),2(f),4(g),6(o)   unitB=L+64: k=1,3,5,7
  // Stash word j (j<16: h0 units 4j..4j+3, j>=16: +64) <-> quad L>>2.

  if (wv == 0) {
    // ===================== L0 recurrence wave =====================
    int q0[32], q1[32], q2[32], q3[32], q4[32], q5[32], q6[32], q7[32];
    float sc[8], bs[8];
    quantW128(Whh0 + (size_t)(lane)       * Hn, q0, sc[0]);
    quantW128(Whh0 + (size_t)(lane + 64)  * Hn, q1, sc[1]);
    quantW128(Whh0 + (size_t)(lane + 128) * Hn, q2, sc[2]);
    quantW128(Whh0 + (size_t)(lane + 192) * Hn, q3, sc[3]);
    quantW128(Whh0 + (size_t)(lane + 256) * Hn, q4, sc[4]);
    quantW128(Whh0 + (size_t)(lane + 320) * Hn, q5, sc[5]);
    quantW128(Whh0 + (size_t)(lane + 384) * Hn, q6, sc[6]);
    quantW128(Whh0 + (size_t)(lane + 448) * Hn, q7, sc[7]);
#pragma unroll
    for (int k = 0; k < 8; ++k) {
      sc[k] *= (1.f / 127.f);  // fold fixed h-scale
      bs[k] = bih0[lane + 64 * k] + bhh0[lane + 64 * k];
    }
    const int shl = 8 * (lane & 3);
    float cA = 0.f, cB = 0.f;
    int wA = 0, wB = 0;  // packed i8 h0 (own quad's words), 0 at t=0
    int fX = 0, fT = 0;
#pragma unroll 1
    for (int t = 0; t < len; ++t) {
      const int tl = t & 15;
      if (tl == 0) POLL_GE(3, (t >> 4) + 1, fX);   // x-proj chunk ready
      POLL_GE(1, t - 3, fT);                       // export slot free (rare)
      // issue x-proj loads now; consumed after the dot (latency hidden)
      const float* xb = &s_xp[(t >> 4) & 1][tl][0][lane];
      float xv0 = xb[0], xv1 = xb[64], xv2 = xb[128], xv3 = xb[192],
            xv4 = xb[256], xv5 = xb[320], xv6 = xb[384], xv7 = xb[448];
      int a0 = 0, a1 = 0, a2 = 0, a3 = 0, a4 = 0, a5 = 0, a6 = 0, a7 = 0;
#pragma unroll
      for (int j = 0; j < 16; ++j) {
        const int s = __builtin_amdgcn_readlane(wA, 4 * j);
        a0 = sdot4(s, q0[j], a0); a1 = sdot4(s, q1[j], a1);
        a2 = sdot4(s, q2[j], a2); a3 = sdot4(s, q3[j], a3);
        a4 = sdot4(s, q4[j], a4); a5 = sdot4(s, q5[j], a5);
        a6 = sdot4(s, q6[j], a6); a7 = sdot4(s, q7[j], a7);
      }
#pragma unroll
      for (int j = 0; j < 16; ++j) {
        const int s = __builtin_amdgcn_readlane(wB, 4 * j);
        a0 = sdot4(s, q0[16 + j], a0); a1 = sdot4(s, q1[16 + j], a1);
        a2 = sdot4(s, q2[16 + j], a2); a3 = sdot4(s, q3[16 + j], a3);
        a4 = sdot4(s, q4[16 + j], a4); a5 = sdot4(s, q5[16 + j], a5);
        a6 = sdot4(s, q6[16 + j], a6); a7 = sdot4(s, q7[16 + j], a7);
      }
      const float gAi = bs[0] + xv0 + (float)a0 * sc[0];
      const float gBi = bs[1] + xv1 + (float)a1 * sc[1];
      const float gAf = bs[2] + xv2 + (float)a2 * sc[2];
      const float gBf = bs[3] + xv3 + (float)a3 * sc[3];
      const float gAg = bs[4] + xv4 + (float)a4 * sc[4];
      const float gBg = bs[5] + xv5 + (float)a5 * sc[5];
      const float gAo = bs[6] + xv6 + (float)a6 * sc[6];
      const float gBo = bs[7] + xv7 + (float)a7 * sc[7];
      cA = sigm(gAf) * cA + sigm(gAi) * tanha(gAg);
      const float hA = sigm(gAo) * tanha(cA);
      cB = sigm(gBf) * cB + sigm(gBi) * tanha(gBg);
      const float hB = sigm(gBo) * tanha(cB);
      // in-register pack: byte -> quad word via DPP or-reduce
      int vA = (((int)__builtin_rintf(hA * 127.f)) & 255) << shl;
      int vB = (((int)__builtin_rintf(hB * 127.f)) & 255) << shl;
      vA |= dpp_x1(vA); vA |= dpp_x2(vA);
      vB |= dpp_x1(vB); vB |= dpp_x2(vB);
      wA = vA; wB = vB;
      if ((lane & 3) == 0) {  // export for TERM wave
        s_h0q[t & 3][lane >> 2]        = vA;
        s_h0q[t & 3][16 + (lane >> 2)] = vB;
      }
      fT = *(volatile int*)&s_flag[1];  // refresh under publish wait
      PUBLISH(0, t + 1);
    }
  } else if (wv == 1) {
    // ===================== L1 recurrence wave =====================
    int q0[32], q1[32], q2[32], q3[32], q4[32], q5[32], q6[32], q7[32];
    float sc[8];
    quantW128(Whh1 + (size_t)(lane)       * Hn, q0, sc[0]);
    quantW128(Whh1 + (size_t)(lane + 64)  * Hn, q1, sc[1]);
    quantW128(Whh1 + (size_t)(lane + 128) * Hn, q2, sc[2]);
    quantW128(Whh1 + (size_t)(lane + 192) * Hn, q3, sc[3]);
    quantW128(Whh1 + (size_t)(lane + 256) * Hn, q4, sc[4]);
    quantW128(Whh1 + (size_t)(lane + 320) * Hn, q5, sc[5]);
    quantW128(Whh1 + (size_t)(lane + 384) * Hn, q6, sc[6]);
    quantW128(Whh1 + (size_t)(lane + 448) * Hn, q7, sc[7]);
#pragma unroll
    for (int k = 0; k < 8; ++k) sc[k] *= (1.f / 127.f);
    const int shl = 8 * (lane & 3);
    float cA = 0.f, cB = 0.f;
    int wA = 0, wB = 0;
    int fT = 0;
#pragma unroll 1
    for (int t = 0; t < len; ++t) {
      POLL_GE(1, t + 1, fT);                       // term(t) ready
      const float* tb = &s_term[t & 3][0][lane];   // hidden under dot
      float tv0 = tb[0], tv1 = tb[64], tv2 = tb[128], tv3 = tb[192],
            tv4 = tb[256], tv5 = tb[320], tv6 = tb[384], tv7 = tb[448];
      int a0 = 0, a1 = 0, a2 = 0, a3 = 0, a4 = 0, a5 = 0, a6 = 0, a7 = 0;
#pragma unroll
      for (int j = 0; j < 16; ++j) {
        const int s = __builtin_amdgcn_readlane(wA, 4 * j);
        a0 = sdot4(s, q0[j], a0); a1 = sdot4(s, q1[j], a1);
        a2 = sdot4(s, q2[j], a2); a3 = sdot4(s, q3[j], a3);
        a4 = sdot4(s, q4[j], a4); a5 = sdot4(s, q5[j], a5);
        a6 = sdot4(s, q6[j], a6); a7 = sdot4(s, q7[j], a7);
      }
#pragma unroll
      for (int j = 0; j < 16; ++j) {
        const int s = __builtin_amdgcn_readlane(wB, 4 * j);
        a0 = sdot4(s, q0[16 + j], a0); a1 = sdot4(s, q1[16 + j], a1);
        a2 = sdot4(s, q2[16 + j], a2); a3 = sdot4(s, q3[16 + j], a3);
        a4 = sdot4(s, q4[16 + j], a4); a5 = sdot4(s, q5[16 + j], a5);
        a6 = sdot4(s, q6[16 + j], a6); a7 = sdot4(s, q7[16 + j], a7);
      }
      const float gAi = tv0 + (float)a0 * sc[0];
      const float gBi = tv1 + (float)a1 * sc[1];
      const float gAf = tv2 + (float)a2 * sc[2];
      const float gBf = tv3 + (float)a3 * sc[3];
      const float gAg = tv4 + (float)a4 * sc[4];
      const float gBg = tv5 + (float)a5 * sc[5];
      const float gAo = tv6 + (float)a6 * sc[6];
      const float gBo = tv7 + (float)a7 * sc[7];
      cA = sigm(gAf) * cA + sigm(gAi) * tanha(gAg);
      const float hA = sigm(gAo) * tanha(cA);
      cB = sigm(gBf) * cB + sigm(gBi) * tanha(gBg);
      const float hB = sigm(gBo) * tanha(cB);
      if (t == len - 1) { s_h1f[lane] = hA; s_h1f[lane + 64] = hB; }
      int vA = (((int)__builtin_rintf(hA * 127.f)) & 255) << shl;
      int vB = (((int)__builtin_rintf(hB * 127.f)) & 255) << shl;
      vA |= dpp_x1(vA); vA |= dpp_x2(vA);
      vB |= dpp_x1(vB); vB |= dpp_x2(vB);
      wA = vA; wB = vB;
      fT = *(volatile int*)&s_flag[1];
      PUBLISH(2, t + 1);                           // frees term ring slot
    }
  } else if (wv == 2) {
    // ===================== TERM wave: Wih1 . h0(t) =====================
    int q0[32], q1[32], q2[32], q3[32], q4[32], q5[32], q6[32], q7[32];
    float sc[8], bs[8];
    quantW128(Wih1 + (size_t)(lane)       * Hn, q0, sc[0]);
    quantW128(Wih1 + (size_t)(lane + 64)  * Hn, q1, sc[1]);
    quantW128(Wih1 + (size_t)(lane + 128) * Hn, q2, sc[2]);
    quantW128(Wih1 + (size_t)(lane + 192) * Hn, q3, sc[3]);
    quantW128(Wih1 + (size_t)(lane + 256) * Hn, q4, sc[4]);
    quantW128(Wih1 + (size_t)(lane + 320) * Hn, q5, sc[5]);
    quantW128(Wih1 + (size_t)(lane + 384) * Hn, q6, sc[6]);
    quantW128(Wih1 + (size_t)(lane + 448) * Hn, q7, sc[7]);
#pragma unroll
    for (int k = 0; k < 8; ++k) {
      sc[k] *= (1.f / 127.f);
      bs[k] = bih1[lane + 64 * k] + bhh1[lane + 64 * k];
    }
    int fL0 = 0, fL1 = 0;
#pragma unroll 1
    for (int t = 0; t < len; ++t) {
      POLL_GE(0, t + 1, fL0);                      // h0(t) exported
      POLL_GE(2, t - 3, fL1);                      // term slot free (rare)
      const int vq = s_h0q[t & 3][lane & 31];
      int a0 = 0, a1 = 0, a2 = 0, a3 = 0, a4 = 0, a5 = 0, a6 = 0, a7 = 0;
#pragma unroll
      for (int j = 0; j < 32; ++j) {
        const int s = __builtin_amdgcn_readlane(vq, j);
        a0 = sdot4(s, q0[j], a0); a1 = sdot4(s, q1[j], a1);
        a2 = sdot4(s, q2[j], a2); a3 = sdot4(s, q3[j], a3);
        a4 = sdot4(s, q4[j], a4); a5 = sdot4(s, q5[j], a5);
        a6 = sdot4(s, q6[j], a6); a7 = sdot4(s, q7[j], a7);
      }
      float* tb = &s_term[t & 3][0][lane];
      tb[0]   = bs[0] + (float)a0 * sc[0];
      tb[64]  = bs[1] + (float)a1 * sc[1];
      tb[128] = bs[2] + (float)a2 * sc[2];
      tb[192] = bs[3] + (float)a3 * sc[3];
      tb[256] = bs[4] + (float)a4 * sc[4];
      tb[320] = bs[5] + (float)a5 * sc[5];
      tb[384] = bs[6] + (float)a6 * sc[6];
      tb[448] = bs[7] + (float)a7 * sc[7];
      fL0 = *(volatile int*)&s_flag[0];
      fL1 = *(volatile int*)&s_flag[2];
      PUBLISH(1, t + 1);
    }
  } else {
    // ===================== XP wave: x -> f16 -> Wih0 projection =========
    int wp0[20], wp1[20], wp2[20], wp3[20], wp4[20], wp5[20], wp6[20], wp7[20];
    {
      const float* p;
      p = Wih0 + (size_t)(lane)       * Dn;
#pragma unroll
      for (int w = 0; w < 20; ++w) wp0[w] = pk2i(p[2 * w], p[2 * w + 1]);
      p = Wih0 + (size_t)(lane + 64)  * Dn;
#pragma unroll
      for (int w = 0; w < 20; ++w) wp1[w] = pk2i(p[2 * w], p[2 * w + 1]);
      p = Wih0 + (size_t)(lane + 128) * Dn;
#pragma unroll
      for (int w = 0; w < 20; ++w) wp2[w] = pk2i(p[2 * w], p[2 * w + 1]);
      p = Wih0 + (size_t)(lane + 192) * Dn;
#pragma unroll
      for (int w = 0; w < 20; ++w) wp3[w] = pk2i(p[2 * w], p[2 * w + 1]);
      p = Wih0 + (size_t)(lane + 256) * Dn;
#pragma unroll
      for (int w = 0; w < 20; ++w) wp4[w] = pk2i(p[2 * w], p[2 * w + 1]);
      p = Wih0 + (size_t)(lane + 320) * Dn;
#pragma unroll
      for (int w = 0; w < 20; ++w) wp5[w] = pk2i(p[2 * w], p[2 * w + 1]);
      p = Wih0 + (size_t)(lane + 384) * Dn;
#pragma unroll
      for (int w = 0; w < 20; ++w) wp6[w] = pk2i(p[2 * w], p[2 * w + 1]);
      p = Wih0 + (size_t)(lane + 448) * Dn;
#pragma unroll
      for (int w = 0; w < 20; ++w) wp7[w] = pk2i(p[2 * w], p[2 * w + 1]);
    }
    const int nch = (len + 15) >> 4;  // chunks to produce (<=128)
    // chunk 0: load + convert
    {
      const float* src = x + (size_t)b * Tn * Dn;
#if HAVE_GLDS
      gl_lds16(src + lane * 4,        &s_xraw[lane * 4]);
      gl_lds16(src + (lane + 64) * 4, &s_xraw[(lane + 64) * 4]);
      if (lane < 32)
        gl_lds16(src + (lane + 128) * 4, &s_xraw[(lane + 128) * 4]);
      asm volatile("s_waitcnt vmcnt(0)" ::: "memory");
#else
      *(float4*)&s_xraw[lane * 4] = *(const float4*)(src + lane * 4);
      *(float4*)&s_xraw[(lane + 64) * 4] = *(const float4*)(src + (lane + 64) * 4);
      if (lane < 32)
        *(float4*)&s_xraw[(lane + 128) * 4] = *(const float4*)(src + (lane + 128) * 4);
#endif
      {
        float4 v = *(const float4*)&s_xraw[4 * lane];
        s_xh2[2 * lane] = pk2i(v.x, v.y); s_xh2[2 * lane + 1] = pk2i(v.z, v.w);
        v = *(const float4*)&s_xraw[4 * (lane + 64)];
        s_xh2[2 * (lane + 64)] = pk2i(v.x, v.y);
        s_xh2[2 * (lane + 64) + 1] = pk2i(v.z, v.w);
        if (lane < 32) {
          v = *(const float4*)&s_xraw[4 * (lane + 128)];
          s_xh2[2 * (lane + 128)] = pk2i(v.x, v.y);
          s_xh2[2 * (lane + 128) + 1] = pk2i(v.z, v.w);
        }
      }
    }
    int fL0 = 0;
#pragma unroll 1
    for (int k = 0; k < nch; ++k) {
      const bool more = (k + 1 < nch);
      if (more) {  // prefetch next raw chunk (latency hides under project)
        const float* src = x + ((size_t)b * Tn + (size_t)(k + 1) * 16) * Dn;
#if HAVE_GLDS
        gl_lds16(src + lane * 4,        &s_xraw[lane * 4]);
        gl_lds16(src + (lane + 64) * 4, &s_xraw[(lane + 64) * 4]);
        if (lane < 32)
          gl_lds16(src + (lane + 128) * 4, &s_xraw[(lane + 128) * 4]);
#else
        *(float4*)&s_xraw[lane * 4] = *(const float4*)(src + lane * 4);
        *(float4*)&s_xraw[(lane + 64) * 4] = *(const float4*)(src + (lane + 64) * 4);
        if (lane < 32)
          *(float4*)&s_xraw[(lane + 128) * 4] = *(const float4*)(src + (lane + 128) * 4);
#endif
      }
      // project chunk k from s_xh2
      {
        const int* flat = s_xh2;
        const int st0 = flat[lane], st1 = flat[lane + 64],
                  st2 = flat[lane + 128], st3 = flat[lane + 192],
                  st4 = flat[lane + 256];
#pragma unroll 1
        for (int tl = 0; tl < 16; ++tl) {
          float a0 = 0.f, a1 = 0.f, a2 = 0.f, a3 = 0.f,
                a4 = 0.f, a5 = 0.f, a6 = 0.f, a7 = 0.f;
#pragma unroll
          for (int w = 0; w < 20; ++w) {
            const h2 s = bch(RLST(20 * tl + w));
            a0 = fdot2f(s, bch(wp0[w]), a0); a1 = fdot2f(s, bch(wp1[w]), a1);
            a2 = fdot2f(s, bch(wp2[w]), a2); a3 = fdot2f(s, bch(wp3[w]), a3);
            a4 = fdot2f(s, bch(wp4[w]), a4); a5 = fdot2f(s, bch(wp5[w]), a5);
            a6 = fdot2f(s, bch(wp6[w]), a6); a7 = fdot2f(s, bch(wp7[w]), a7);
          }
          float* xb = &s_xp[k & 1][tl][0][lane];
          xb[0] = a0;   xb[64] = a1;  xb[128] = a2; xb[192] = a3;
          xb[256] = a4; xb[320] = a5; xb[384] = a6; xb[448] = a7;
        }
      }
      PUBLISH(3, k + 1);
      if (more) {
        POLL_GE(0, 16 * k, fL0);  // L0 done with the buffer we overwrite next
#if HAVE_GLDS
        asm volatile("s_waitcnt vmcnt(0)" ::: "memory");
#endif
        float4 v = *(const float4*)&s_xraw[4 * lane];
        s_xh2[2 * lane] = pk2i(v.x, v.y); s_xh2[2 * lane + 1] = pk2i(v.z, v.w);
        v = *(const float4*)&s_xraw[4 * (lane + 64)];
        s_xh2[2 * (lane + 64)] = pk2i(v.x, v.y);
        s_xh2[2 * (lane + 64) + 1] = pk2i(v.z, v.w);
        if (lane < 32) {
          v = *(const float4*)&s_xraw[4 * (lane + 128)];
          s_xh2[2 * (lane + 128)] = pk2i(v.x, v.y);
          s_xh2[2 * (lane + 128) + 1] = pk2i(v.z, v.w);
        }
      }
    }
  }

  __syncthreads();  // all chains done; s_h1f complete

  // ---- LayerNorm over H on wave 0 ----
  if (tid < 64) {
    const float a = s_h1f[tid], d = s_h1f[64 + tid];
    float s = a + d, q = a * a + d * d;
#pragma unroll
    for (int m = 32; m >= 1; m >>= 1) {
      s += __shfl_xor(s, m, 64);
      q += __shfl_xor(q, m, 64);
    }
    const float mu = s * (1.f / 128.f);
    float var = q * (1.f / 128.f) - mu * mu;
    var = fmaxf(var, 0.f);
    const float rstd = rsqrtf(var + 1e-5f);
    s_hn[tid]      = (a - mu) * rstd * gam[tid]      + bet[tid];
    s_hn[64 + tid] = (d - mu) * rstd * gam[64 + tid] + bet[64 + tid];
  }
  __syncthreads();

  // ---- FC head ----
  if (tid < Cn) {
    float acc = fcb[tid];
    const float* wp = fcw + tid * Hn;
#pragma unroll 4
    for (int k = 0; k < Hn; ++k) acc += s_hn[k] * wp[k];
    out[(size_t)b * Cn + tid] = acc;
  }
}

extern "C" void kernel_launch(void* const* d_in, const int* in_sizes, int n_in,
                              void* d_out, int out_size, void* d_ws, size_t ws_size,
                              hipStream_t stream) {
  (void)in_sizes; (void)n_in; (void)d_ws; (void)ws_size; (void)out_size;
  lstm2_fused<<<dim3(Bn), dim3(256), 0, stream>>>(
      (const float*)d_in[0],  (const int*)d_in[1],
      (const float*)d_in[2],  (const float*)d_in[3],
      (const float*)d_in[4],  (const float*)d_in[5],
      (const float*)d_in[6],  (const float*)d_in[7],
      (const float*)d_in[8],  (const float*)d_in[9],
      (const float*)d_in[10], (const float*)d_in[11],
      (const float*)d_in[12], (const float*)d_in[13],
      (float*)d_out);
}